// Round 13
// baseline (122.670 us; speedup 1.0000x reference)
//
#include <hip/hip_runtime.h>
#include <hip/hip_bf16.h>
#include <stdint.h>

typedef __bf16 bf16x8 __attribute__((ext_vector_type(8)));
typedef float  f32x4  __attribute__((ext_vector_type(4)));

constexpr int Bb = 4;      // batch
constexpr int Tt = 1024;   // tokens
constexpr int Cc = 1024;   // channels
constexpr int Kk = 16;     // sparse K
constexpr int HK = 256;    // heads*keys
constexpr int KSPL = 8;    // K1 k-split factor

__device__ inline __bf16 f2bf(float f) {
    union { __hip_bfloat16 h; __bf16 b; } u;
    u.h = __float2bfloat16(f);
    return u.b;
}

// Async global->LDS, 16B/lane; LDS dest = wave-uniform base + lane*16 (m104).
__device__ inline void load_lds16(const void* g, void* l) {
    auto gp = (const __attribute__((address_space(1))) unsigned int*)(uintptr_t)g;
    auto lp = (__attribute__((address_space(3))) unsigned int*)(uintptr_t)l;
    __builtin_amdgcn_global_load_lds(gp, lp, 16, 0, 0);
}

// 8 consecutive fp32 (global) -> bf16x8.
__device__ inline bf16x8 cvt8(const float* p) {
    f32x4 lo = *reinterpret_cast<const f32x4*>(p);
    f32x4 hi = *reinterpret_cast<const f32x4*>(p + 4);
    bf16x8 r;
    r[0] = f2bf(lo[0]); r[1] = f2bf(lo[1]); r[2] = f2bf(lo[2]); r[3] = f2bf(lo[3]);
    r[4] = f2bf(hi[0]); r[5] = f2bf(hi[1]); r[6] = f2bf(hi[2]); r[7] = f2bf(hi[3]);
    return r;
}

// K1: kv partials. kv_part[kz][64][2048] = x_sel[64x128k] @ Wkv^T[2048x128k].
// K-split x8 -> grid (32,1,8) = 256 blocks, 4 iters each. Unchanged from R12.
__global__ __launch_bounds__(256)
void kv_gemm(const float* __restrict__ x, const float* __restrict__ Wkv,
             float* __restrict__ kv_part)
{
    __shared__ __hip_bfloat16 As[64 * 40];
    __shared__ __hip_bfloat16 Bs[64 * 40];
    const int tid = threadIdx.x;
    const int lane = tid & 63;
    const int wave = tid >> 6;
    const int wm = wave >> 1, wn = wave & 1;
    const int tileN = blockIdx.x * 64;
    const int kz = blockIdx.z;
    const int r16 = lane & 15;
    const int kq  = (lane >> 4) * 8;

    const int sr = tid >> 2, sc = (tid & 3) * 8;
    const size_t arow = (size_t)(sr >> 4) * Tt + (sr & 15);   // gather: first 16 tokens/batch

    f32x4 acc[2][2] = {};
    for (int kk = kz * 128; kk < kz * 128 + 128; kk += 32) {
        *reinterpret_cast<bf16x8*>(As + sr * 40 + sc) = cvt8(x + arow * Cc + kk + sc);
        *reinterpret_cast<bf16x8*>(Bs + sr * 40 + sc) = cvt8(Wkv + (size_t)(tileN + sr) * Cc + kk + sc);
        __syncthreads();
        bf16x8 a[2], b[2];
#pragma unroll
        for (int i = 0; i < 2; ++i) {
            a[i] = *reinterpret_cast<const bf16x8*>(As + (wm * 32 + i * 16 + r16) * 40 + kq);
            b[i] = *reinterpret_cast<const bf16x8*>(Bs + (wn * 32 + i * 16 + r16) * 40 + kq);
        }
#pragma unroll
        for (int i = 0; i < 2; ++i)
#pragma unroll
            for (int j = 0; j < 2; ++j)
                acc[i][j] = __builtin_amdgcn_mfma_f32_16x16x32_bf16(a[i], b[j], acc[i][j], 0, 0, 0);
        __syncthreads();
    }

    const int crow0 = (lane >> 4) * 4;
    const int ccol  = lane & 15;
    float* outp = kv_part + (size_t)kz * 64 * 2048;
#pragma unroll
    for (int i = 0; i < 2; ++i)
#pragma unroll
        for (int j = 0; j < 2; ++j)
#pragma unroll
            for (int r = 0; r < 4; ++r)
                outp[(size_t)(wm * 32 + i * 16 + crow0 + r) * 2048
                     + tileN + wn * 32 + j * 16 + ccol] = acc[i][j][r];
}

// K2: QK / vPt precompute; sel = sum of 8 kv partials. Unchanged from R12.
__global__ __launch_bounds__(256)
void precompute(const float* __restrict__ kv_part,  // [8][64][2048]
                const float* __restrict__ W_attn,   // rows 0..1023 = Wq
                const float* __restrict__ W_proj,
                __hip_bfloat16* __restrict__ QKb,   // [Bb][256][1024]
                __hip_bfloat16* __restrict__ vPt)   // [Bb][1024][256]
{
    __shared__ float sel[64][16];   // [d][k]
    const int blk = blockIdx.x;
    const int type = blk >> 8;
    const int bh = (blk >> 2) & 63;
    const int cchunk = blk & 3;
    const int b = bh >> 4, h = bh & 15;
    const int tid = threadIdx.x;

    for (int e = tid; e < Kk * 64; e += 256) {
        int k = e >> 6, d = e & 63;
        size_t off = (size_t)(b * Kk + k) * 2048 + type * 1024 + h * 64 + d;
        float s = 0.f;
#pragma unroll
        for (int p = 0; p < KSPL; ++p) s += kv_part[off + (size_t)p * 64 * 2048];
        sel[d][k] = s;
    }
    __syncthreads();

    const int c = cchunk * 256 + tid;
    float acc[Kk] = {};

    if (type == 0) {
        const float* wp = W_attn + (size_t)(h * 64) * 1024 + c;
#pragma unroll 8
        for (int d = 0; d < 64; ++d) {
            float wv = wp[(size_t)d * 1024];
            const float4* sv = reinterpret_cast<const float4*>(sel[d]);
            float4 s0 = sv[0], s1 = sv[1], s2 = sv[2], s3 = sv[3];
            acc[0]  += wv * s0.x; acc[1]  += wv * s0.y; acc[2]  += wv * s0.z; acc[3]  += wv * s0.w;
            acc[4]  += wv * s1.x; acc[5]  += wv * s1.y; acc[6]  += wv * s1.z; acc[7]  += wv * s1.w;
            acc[8]  += wv * s2.x; acc[9]  += wv * s2.y; acc[10] += wv * s2.z; acc[11] += wv * s2.w;
            acc[12] += wv * s3.x; acc[13] += wv * s3.y; acc[14] += wv * s3.z; acc[15] += wv * s3.w;
        }
#pragma unroll
        for (int k = 0; k < Kk; ++k)
            QKb[((size_t)b * HK + h * 16 + k) * 1024 + c] = __float2bfloat16(acc[k]);
    } else {
        const float* wrow = W_proj + (size_t)c * 1024 + h * 64;
#pragma unroll 8
        for (int d4 = 0; d4 < 64; d4 += 4) {
            float4 wv = *reinterpret_cast<const float4*>(wrow + d4);
            const float w4[4] = {wv.x, wv.y, wv.z, wv.w};
#pragma unroll
            for (int dd = 0; dd < 4; ++dd) {
                float wvv = w4[dd];
                const float4* sv = reinterpret_cast<const float4*>(sel[d4 + dd]);
                float4 s0 = sv[0], s1 = sv[1], s2 = sv[2], s3 = sv[3];
                acc[0]  += wvv * s0.x; acc[1]  += wvv * s0.y; acc[2]  += wvv * s0.z; acc[3]  += wvv * s0.w;
                acc[4]  += wvv * s1.x; acc[5]  += wvv * s1.y; acc[6]  += wvv * s1.z; acc[7]  += wvv * s1.w;
                acc[8]  += wvv * s2.x; acc[9]  += wvv * s2.y; acc[10] += wvv * s2.z; acc[11] += wvv * s2.w;
                acc[12] += wvv * s3.x; acc[13] += wvv * s3.y; acc[14] += wvv * s3.z; acc[15] += wvv * s3.w;
            }
        }
        bf16x8 p0, p1;
#pragma unroll
        for (int k = 0; k < 8; ++k) { p0[k] = f2bf(acc[k]); p1[k] = f2bf(acc[k + 8]); }
        __hip_bfloat16* dst = vPt + ((size_t)b * 1024 + c) * HK + h * 16;
        *reinterpret_cast<bf16x8*>(dst) = p0;
        *reinterpret_cast<bf16x8*>(dst + 8) = p1;
    }
}

// K3: logits + fused masked softmax. ROUND-13: 32x32 tiles -> grid (8,32,4) =
// 1024 blocks = 4/CU (was 2/CU). BK=64 (16 iters); wave tile 16x16.
// B DMA half-select is wave-uniform (half = wave>>1) per m104.
__global__ __launch_bounds__(256)
void logits_softmax(const float* __restrict__ x,
                    const __hip_bfloat16* __restrict__ QKb,
                    __hip_bfloat16* __restrict__ wout)
{
    __shared__ __hip_bfloat16 Ah[2][32 * 40];   // fp32->bf16 staged x, padded
    __shared__ __hip_bfloat16 Bh[2][32 * 32];   // QK halves, 64B stride (2-way, free)

    const float* A = x + (size_t)blockIdx.z * Tt * Cc;
    const __hip_bfloat16* Bm = QKb + (size_t)blockIdx.z * HK * Cc;

    const int tid = threadIdx.x;
    const int lane = tid & 63;
    const int wave = tid >> 6;
    const int wm = wave >> 1, wn = wave & 1;
    const int tileM = blockIdx.y * 32;
    const int tileN = blockIdx.x * 32;
    const int r16 = lane & 15;
    const int kq  = (lane >> 4) * 8;

    // A-staging: thread -> row tid>>3 (0..31), cols (tid&7)*8 of the 64-wide k-slab.
    const int ar = tid >> 3, ac = (tid & 7) * 8;
    const int ahalf = ac >> 5, acol = ac & 31;
    // B-staging: 256 chunks over 2 halves; half = wave>>1 (uniform), local chunk
    // gg = (wave&1)*64 + lane -> row gg>>2, col (gg&3)*8.
    const int bhalf = wave >> 1;
    const int gg = (wave & 1) * 64 + lane;
    const int br = gg >> 2, bc = (gg & 3) * 8;

    f32x4 acc = {};
    for (int kk = 0; kk < Cc; kk += 64) {
        load_lds16(Bm + (size_t)(tileN + br) * Cc + kk + bhalf * 32 + bc,
                   &Bh[bhalf][0] + gg * 8);
        *reinterpret_cast<bf16x8*>(&Ah[ahalf][0] + ar * 40 + acol) =
            cvt8(A + (size_t)(tileM + ar) * Cc + kk + ac);
        __syncthreads();

#pragma unroll
        for (int s = 0; s < 2; ++s) {
            bf16x8 a = *reinterpret_cast<const bf16x8*>(&Ah[s][0] + (wm * 16 + r16) * 40 + kq);
            bf16x8 b = *reinterpret_cast<const bf16x8*>(&Bh[s][0] + (wn * 16 + r16) * 32 + kq);
            acc = __builtin_amdgcn_mfma_f32_16x16x32_bf16(a, b, acc, 0, 0, 0);
        }
        __syncthreads();
    }

    const int crow0 = (lane >> 4) * 4;
    const int ccol  = lane & 15;        // k index within the head
#pragma unroll
    for (int r = 0; r < 4; ++r) {
        int t = tileM + wm * 16 + crow0 + r;
        bool valid = (ccol <= t);
        int hk = tileN + wn * 16 + ccol;
        float v = acc[r] * 0.125f;
        float vm = valid ? v : -3.0e38f;
#pragma unroll
        for (int m = 1; m < 16; m <<= 1) vm = fmaxf(vm, __shfl_xor(vm, m));
        float e = valid ? __expf(v - vm) : 0.f;
        float s = e;
#pragma unroll
        for (int m = 1; m < 16; m <<= 1) s += __shfl_xor(s, m);
        wout[((size_t)blockIdx.z * Tt + t) * HK + hk] = __float2bfloat16(e / s);
    }
}

// K4: out[b] = w[b] @ vPt[b]^T (M=1024, N=1024, K=256). Unchanged from R12.
__global__ __launch_bounds__(256)
void out_gemm(const __hip_bfloat16* __restrict__ Aw,
              const __hip_bfloat16* __restrict__ Bv,
              float* __restrict__ Cout)
{
    __shared__ __hip_bfloat16 As[64 * 32];
    __shared__ __hip_bfloat16 Bs[64 * 32];

    const __hip_bfloat16* A = Aw + (size_t)blockIdx.z * Tt * HK;
    const __hip_bfloat16* Bm = Bv + (size_t)blockIdx.z * Cc * HK;

    const int lane = threadIdx.x & 63;
    const int wave = threadIdx.x >> 6;
    const int wm = wave >> 1, wn = wave & 1;
    const int tileM = blockIdx.y * 64;
    const int tileN = blockIdx.x * 64;
    const int r16 = lane & 15;
    const int kq  = (lane >> 4) * 8;

    f32x4 acc[2][2] = {};
    for (int kk = 0; kk < HK; kk += 32) {
        {
            int g = wave * 64 + lane;      // row g>>2, col (g&3)*8
            load_lds16(A + (size_t)(tileM + (g >> 2)) * HK + kk + (g & 3) * 8,
                       As + wave * 512);
            load_lds16(Bm + (size_t)(tileN + (g >> 2)) * HK + kk + (g & 3) * 8,
                       Bs + wave * 512);
        }
        __syncthreads();
        bf16x8 a[2], b[2];
#pragma unroll
        for (int i = 0; i < 2; ++i) {
            a[i] = *reinterpret_cast<const bf16x8*>(As + (wm * 32 + i * 16 + r16) * 32 + kq);
            b[i] = *reinterpret_cast<const bf16x8*>(Bs + (wn * 32 + i * 16 + r16) * 32 + kq);
        }
#pragma unroll
        for (int i = 0; i < 2; ++i)
#pragma unroll
            for (int j = 0; j < 2; ++j)
                acc[i][j] = __builtin_amdgcn_mfma_f32_16x16x32_bf16(a[i], b[j], acc[i][j], 0, 0, 0);
        __syncthreads();
    }

    const int crow0 = (lane >> 4) * 4;
    const int ccol  = lane & 15;
    float* outp = Cout + (size_t)blockIdx.z * Tt * Cc;
#pragma unroll
    for (int i = 0; i < 2; ++i)
#pragma unroll
        for (int j = 0; j < 2; ++j)
#pragma unroll
            for (int r = 0; r < 4; ++r)
                outp[(size_t)(tileM + wm * 32 + i * 16 + crow0 + r) * Cc
                     + tileN + wn * 32 + j * 16 + ccol] = acc[i][j][r];
}

extern "C" void kernel_launch(void* const* d_in, const int* in_sizes, int n_in,
                              void* d_out, int out_size, void* d_ws, size_t ws_size,
                              hipStream_t stream)
{
    (void)in_sizes; (void)n_in; (void)out_size; (void)ws_size;
    const float* x      = (const float*)d_in[0];
    const float* W_attn = (const float*)d_in[1];
    const float* W_proj = (const float*)d_in[2];
    // d_in[3] = W_rel dead (round-4 verified): top_k values discarded; only
    // finite score at col 0 -> idx = [0..15] for every (h,t).
    float* out = (float*)d_out;

    char* ws = (char*)d_ws;
    float*          kv_part = (float*)ws;                        // 4 MB [8][64][2048]
    __hip_bfloat16* QKb  = (__hip_bfloat16*)(ws + (4u << 20));   // 2 MB [4][256][1024]
    __hip_bfloat16* vPt  = (__hip_bfloat16*)(ws + (6u << 20));   // 2 MB [4][1024][256]
    __hip_bfloat16* w_ws = (__hip_bfloat16*)(ws + (8u << 20));   // 2 MB [4][1024][256]

    // K1: kv partials (fp32 in, VGPR-cvt bf16 staging; K split x8 -> 256 blocks).
    kv_gemm<<<dim3(32, 1, KSPL), 256, 0, stream>>>(x, W_attn + (size_t)Cc * Cc, kv_part);
    // K2: QK / vPt precompute (sums 8 kv partials; fp32 math, bf16 out).
    precompute<<<512, 256, 0, stream>>>(kv_part, W_attn, W_proj, QKb, vPt);
    // K3: logits GEMM + fused masked softmax -> w. 1024 blocks (4/CU), BK=64.
    logits_softmax<<<dim3(HK / 32, Tt / 32, Bb), 256, 0, stream>>>(x, QKb, w_ws);
    // K4: out = w @ vPt^T -> d_out fp32. 1024 blocks (4/CU).
    out_gemm<<<dim3(16, 16, Bb), 256, 0, stream>>>(w_ws, vPt, out);
}

// Round 14
// 116.079 us; speedup vs baseline: 1.0568x; 1.0568x over previous
//
#include <hip/hip_runtime.h>
#include <hip/hip_bf16.h>
#include <stdint.h>

typedef __bf16 bf16x8 __attribute__((ext_vector_type(8)));
typedef float  f32x4  __attribute__((ext_vector_type(4)));

constexpr int Bb = 4;      // batch
constexpr int Tt = 1024;   // tokens
constexpr int Cc = 1024;   // channels
constexpr int Kk = 16;     // sparse K
constexpr int HK = 256;    // heads*keys
constexpr int KSPL = 8;    // K1 k-split factor

__device__ inline __bf16 f2bf(float f) {
    union { __hip_bfloat16 h; __bf16 b; } u;
    u.h = __float2bfloat16(f);
    return u.b;
}

// Async global->LDS, 16B/lane; LDS dest = wave-uniform base + lane*16 (m104).
__device__ inline void load_lds16(const void* g, void* l) {
    auto gp = (const __attribute__((address_space(1))) unsigned int*)(uintptr_t)g;
    auto lp = (__attribute__((address_space(3))) unsigned int*)(uintptr_t)l;
    __builtin_amdgcn_global_load_lds(gp, lp, 16, 0, 0);
}

// 8 consecutive fp32 (global) -> bf16x8.
__device__ inline bf16x8 cvt8(const float* p) {
    f32x4 lo = *reinterpret_cast<const f32x4*>(p);
    f32x4 hi = *reinterpret_cast<const f32x4*>(p + 4);
    bf16x8 r;
    r[0] = f2bf(lo[0]); r[1] = f2bf(lo[1]); r[2] = f2bf(lo[2]); r[3] = f2bf(lo[3]);
    r[4] = f2bf(hi[0]); r[5] = f2bf(hi[1]); r[6] = f2bf(hi[2]); r[7] = f2bf(hi[3]);
    return r;
}

// K1: kv partials. kv_part[kz][64][2048] = x_sel[64x128k] @ Wkv^T[2048x128k].
// K-split x8 -> grid (32,1,8) = 256 blocks, 4 iters each.
// fp32 staged via VGPR-cvt into padded bf16 LDS (stride 40 = 80B, conflict-free).
__global__ __launch_bounds__(256)
void kv_gemm(const float* __restrict__ x, const float* __restrict__ Wkv,
             float* __restrict__ kv_part)
{
    __shared__ __hip_bfloat16 As[64 * 40];
    __shared__ __hip_bfloat16 Bs[64 * 40];
    const int tid = threadIdx.x;
    const int lane = tid & 63;
    const int wave = tid >> 6;
    const int wm = wave >> 1, wn = wave & 1;
    const int tileN = blockIdx.x * 64;
    const int kz = blockIdx.z;
    const int r16 = lane & 15;
    const int kq  = (lane >> 4) * 8;

    const int sr = tid >> 2, sc = (tid & 3) * 8;
    const size_t arow = (size_t)(sr >> 4) * Tt + (sr & 15);   // gather: first 16 tokens/batch

    f32x4 acc[2][2] = {};
    for (int kk = kz * 128; kk < kz * 128 + 128; kk += 32) {
        *reinterpret_cast<bf16x8*>(As + sr * 40 + sc) = cvt8(x + arow * Cc + kk + sc);
        *reinterpret_cast<bf16x8*>(Bs + sr * 40 + sc) = cvt8(Wkv + (size_t)(tileN + sr) * Cc + kk + sc);
        __syncthreads();
        bf16x8 a[2], b[2];
#pragma unroll
        for (int i = 0; i < 2; ++i) {
            a[i] = *reinterpret_cast<const bf16x8*>(As + (wm * 32 + i * 16 + r16) * 40 + kq);
            b[i] = *reinterpret_cast<const bf16x8*>(Bs + (wn * 32 + i * 16 + r16) * 40 + kq);
        }
#pragma unroll
        for (int i = 0; i < 2; ++i)
#pragma unroll
            for (int j = 0; j < 2; ++j)
                acc[i][j] = __builtin_amdgcn_mfma_f32_16x16x32_bf16(a[i], b[j], acc[i][j], 0, 0, 0);
        __syncthreads();
    }

    const int crow0 = (lane >> 4) * 4;
    const int ccol  = lane & 15;
    float* outp = kv_part + (size_t)kz * 64 * 2048;
#pragma unroll
    for (int i = 0; i < 2; ++i)
#pragma unroll
        for (int j = 0; j < 2; ++j)
#pragma unroll
            for (int r = 0; r < 4; ++r)
                outp[(size_t)(wm * 32 + i * 16 + crow0 + r) * 2048
                     + tileN + wn * 32 + j * 16 + ccol] = acc[i][j][r];
}

// K2: QK / vPt precompute; sel = sum of 8 kv partials. Grid 512. Unroll 8.
__global__ __launch_bounds__(256)
void precompute(const float* __restrict__ kv_part,  // [8][64][2048]
                const float* __restrict__ W_attn,   // rows 0..1023 = Wq
                const float* __restrict__ W_proj,
                __hip_bfloat16* __restrict__ QKb,   // [Bb][256][1024]
                __hip_bfloat16* __restrict__ vPt)   // [Bb][1024][256]
{
    __shared__ float sel[64][16];   // [d][k]
    const int blk = blockIdx.x;
    const int type = blk >> 8;
    const int bh = (blk >> 2) & 63;
    const int cchunk = blk & 3;
    const int b = bh >> 4, h = bh & 15;
    const int tid = threadIdx.x;

    for (int e = tid; e < Kk * 64; e += 256) {
        int k = e >> 6, d = e & 63;
        size_t off = (size_t)(b * Kk + k) * 2048 + type * 1024 + h * 64 + d;
        float s = 0.f;
#pragma unroll
        for (int p = 0; p < KSPL; ++p) s += kv_part[off + (size_t)p * 64 * 2048];
        sel[d][k] = s;
    }
    __syncthreads();

    const int c = cchunk * 256 + tid;
    float acc[Kk] = {};

    if (type == 0) {
        const float* wp = W_attn + (size_t)(h * 64) * 1024 + c;
#pragma unroll 8
        for (int d = 0; d < 64; ++d) {
            float wv = wp[(size_t)d * 1024];
            const float4* sv = reinterpret_cast<const float4*>(sel[d]);
            float4 s0 = sv[0], s1 = sv[1], s2 = sv[2], s3 = sv[3];
            acc[0]  += wv * s0.x; acc[1]  += wv * s0.y; acc[2]  += wv * s0.z; acc[3]  += wv * s0.w;
            acc[4]  += wv * s1.x; acc[5]  += wv * s1.y; acc[6]  += wv * s1.z; acc[7]  += wv * s1.w;
            acc[8]  += wv * s2.x; acc[9]  += wv * s2.y; acc[10] += wv * s2.z; acc[11] += wv * s2.w;
            acc[12] += wv * s3.x; acc[13] += wv * s3.y; acc[14] += wv * s3.z; acc[15] += wv * s3.w;
        }
#pragma unroll
        for (int k = 0; k < Kk; ++k)
            QKb[((size_t)b * HK + h * 16 + k) * 1024 + c] = __float2bfloat16(acc[k]);
    } else {
        const float* wrow = W_proj + (size_t)c * 1024 + h * 64;
#pragma unroll 8
        for (int d4 = 0; d4 < 64; d4 += 4) {
            float4 wv = *reinterpret_cast<const float4*>(wrow + d4);
            const float w4[4] = {wv.x, wv.y, wv.z, wv.w};
#pragma unroll
            for (int dd = 0; dd < 4; ++dd) {
                float wvv = w4[dd];
                const float4* sv = reinterpret_cast<const float4*>(sel[d4 + dd]);
                float4 s0 = sv[0], s1 = sv[1], s2 = sv[2], s3 = sv[3];
                acc[0]  += wvv * s0.x; acc[1]  += wvv * s0.y; acc[2]  += wvv * s0.z; acc[3]  += wvv * s0.w;
                acc[4]  += wvv * s1.x; acc[5]  += wvv * s1.y; acc[6]  += wvv * s1.z; acc[7]  += wvv * s1.w;
                acc[8]  += wvv * s2.x; acc[9]  += wvv * s2.y; acc[10] += wvv * s2.z; acc[11] += wvv * s2.w;
                acc[12] += wvv * s3.x; acc[13] += wvv * s3.y; acc[14] += wvv * s3.z; acc[15] += wvv * s3.w;
            }
        }
        bf16x8 p0, p1;
#pragma unroll
        for (int k = 0; k < 8; ++k) { p0[k] = f2bf(acc[k]); p1[k] = f2bf(acc[k + 8]); }
        __hip_bfloat16* dst = vPt + ((size_t)b * 1024 + c) * HK + h * 16;
        *reinterpret_cast<bf16x8*>(dst) = p0;
        *reinterpret_cast<bf16x8*>(dst + 8) = p1;
    }
}

// K3: logits + fused masked softmax. R12 config (measured best): 64x64 tiles,
// grid (4,32,4) = 512 blocks (2/CU), BK=64 (16 iters).
// R13's 32x32 split regressed (-6 us): doubled barrier-chain iterations and
// halved B reuse. Keep 64x64.
__global__ __launch_bounds__(256)
void logits_softmax(const float* __restrict__ x,
                    const __hip_bfloat16* __restrict__ QKb,
                    __hip_bfloat16* __restrict__ wout)
{
    __shared__ __hip_bfloat16 Ah[2][32 * 40];
    __shared__ __hip_bfloat16 Bh[2][64 * 32];

    const float* A = x + (size_t)blockIdx.z * Tt * Cc;
    const __hip_bfloat16* Bm = QKb + (size_t)blockIdx.z * HK * Cc;

    const int tid = threadIdx.x;
    const int lane = tid & 63;
    const int wave = tid >> 6;
    const int wm = wave >> 1, wn = wave & 1;
    const int tileM = blockIdx.y * 32;
    const int tileN = blockIdx.x * 64;
    const int r16 = lane & 15;
    const int kq  = (lane >> 4) * 8;

    const int ar = tid >> 3, ac = (tid & 7) * 8;
    const int ahalf = ac >> 5, acol = ac & 31;

    f32x4 acc[2] = {};
    for (int kk = 0; kk < Cc; kk += 64) {
#pragma unroll
        for (int h = 0; h < 2; ++h) {
            int g = wave * 64 + lane;
            load_lds16(Bm + (size_t)(tileN + (g >> 2)) * Cc + kk + h * 32 + (g & 3) * 8,
                       &Bh[h][0] + wave * 512);
        }
        *reinterpret_cast<bf16x8*>(&Ah[ahalf][0] + ar * 40 + acol) =
            cvt8(A + (size_t)(tileM + ar) * Cc + kk + ac);
        __syncthreads();

        bf16x8 a[2], b[2][2];
#pragma unroll
        for (int s = 0; s < 2; ++s) {
            a[s] = *reinterpret_cast<const bf16x8*>(&Ah[s][0] + (wm * 16 + r16) * 40 + kq);
#pragma unroll
            for (int j = 0; j < 2; ++j)
                b[s][j] = *reinterpret_cast<const bf16x8*>(
                    &Bh[s][0] + (wn * 32 + j * 16 + r16) * 32 + kq);
        }
#pragma unroll
        for (int s = 0; s < 2; ++s)
#pragma unroll
            for (int j = 0; j < 2; ++j)
                acc[j] = __builtin_amdgcn_mfma_f32_16x16x32_bf16(a[s], b[s][j], acc[j], 0, 0, 0);
        __syncthreads();
    }

    const int crow0 = (lane >> 4) * 4;
    const int ccol  = lane & 15;        // k index within the head
#pragma unroll
    for (int r = 0; r < 4; ++r) {
        int t = tileM + wm * 16 + crow0 + r;
        bool valid = (ccol <= t);
#pragma unroll
        for (int j = 0; j < 2; ++j) {
            int hk = tileN + wn * 32 + j * 16 + ccol;
            float v = acc[j][r] * 0.125f;
            float vm = valid ? v : -3.0e38f;
#pragma unroll
            for (int m = 1; m < 16; m <<= 1) vm = fmaxf(vm, __shfl_xor(vm, m));
            float e = valid ? __expf(v - vm) : 0.f;
            float s = e;
#pragma unroll
            for (int m = 1; m < 16; m <<= 1) s += __shfl_xor(s, m);
            wout[((size_t)blockIdx.z * Tt + t) * HK + hk] = __float2bfloat16(e / s);
        }
    }
}

// K4: out[b] = w[b] @ vPt[b]^T (M=1024, N=1024, K=256), bf16 in, fp32 out.
// 64x64 tiles -> grid (16,16,4) = 1024 blocks = 4/CU.
__global__ __launch_bounds__(256)
void out_gemm(const __hip_bfloat16* __restrict__ Aw,
              const __hip_bfloat16* __restrict__ Bv,
              float* __restrict__ Cout)
{
    __shared__ __hip_bfloat16 As[64 * 32];
    __shared__ __hip_bfloat16 Bs[64 * 32];

    const __hip_bfloat16* A = Aw + (size_t)blockIdx.z * Tt * HK;
    const __hip_bfloat16* Bm = Bv + (size_t)blockIdx.z * Cc * HK;

    const int lane = threadIdx.x & 63;
    const int wave = threadIdx.x >> 6;
    const int wm = wave >> 1, wn = wave & 1;
    const int tileM = blockIdx.y * 64;
    const int tileN = blockIdx.x * 64;
    const int r16 = lane & 15;
    const int kq  = (lane >> 4) * 8;

    f32x4 acc[2][2] = {};
    for (int kk = 0; kk < HK; kk += 32) {
        {
            int g = wave * 64 + lane;      // row g>>2, col (g&3)*8
            load_lds16(A + (size_t)(tileM + (g >> 2)) * HK + kk + (g & 3) * 8,
                       As + wave * 512);
            load_lds16(Bm + (size_t)(tileN + (g >> 2)) * HK + kk + (g & 3) * 8,
                       Bs + wave * 512);
        }
        __syncthreads();
        bf16x8 a[2], b[2];
#pragma unroll
        for (int i = 0; i < 2; ++i) {
            a[i] = *reinterpret_cast<const bf16x8*>(As + (wm * 32 + i * 16 + r16) * 32 + kq);
            b[i] = *reinterpret_cast<const bf16x8*>(Bs + (wn * 32 + i * 16 + r16) * 32 + kq);
        }
#pragma unroll
        for (int i = 0; i < 2; ++i)
#pragma unroll
            for (int j = 0; j < 2; ++j)
                acc[i][j] = __builtin_amdgcn_mfma_f32_16x16x32_bf16(a[i], b[j], acc[i][j], 0, 0, 0);
        __syncthreads();
    }

    const int crow0 = (lane >> 4) * 4;
    const int ccol  = lane & 15;
    float* outp = Cout + (size_t)blockIdx.z * Tt * Cc;
#pragma unroll
    for (int i = 0; i < 2; ++i)
#pragma unroll
        for (int j = 0; j < 2; ++j)
#pragma unroll
            for (int r = 0; r < 4; ++r)
                outp[(size_t)(tileM + wm * 32 + i * 16 + crow0 + r) * Cc
                     + tileN + wn * 32 + j * 16 + ccol] = acc[i][j][r];
}

extern "C" void kernel_launch(void* const* d_in, const int* in_sizes, int n_in,
                              void* d_out, int out_size, void* d_ws, size_t ws_size,
                              hipStream_t stream)
{
    (void)in_sizes; (void)n_in; (void)out_size; (void)ws_size;
    const float* x      = (const float*)d_in[0];
    const float* W_attn = (const float*)d_in[1];
    const float* W_proj = (const float*)d_in[2];
    // d_in[3] = W_rel dead (round-4 verified): top_k values discarded; only
    // finite score at col 0 -> idx = [0..15] for every (h,t).
    float* out = (float*)d_out;

    char* ws = (char*)d_ws;
    float*          kv_part = (float*)ws;                        // 4 MB [8][64][2048]
    __hip_bfloat16* QKb  = (__hip_bfloat16*)(ws + (4u << 20));   // 2 MB [4][256][1024]
    __hip_bfloat16* vPt  = (__hip_bfloat16*)(ws + (6u << 20));   // 2 MB [4][1024][256]
    __hip_bfloat16* w_ws = (__hip_bfloat16*)(ws + (8u << 20));   // 2 MB [4][1024][256]

    // K1: kv partials (fp32 in, VGPR-cvt bf16 staging; K split x8 -> 256 blocks).
    kv_gemm<<<dim3(32, 1, KSPL), 256, 0, stream>>>(x, W_attn + (size_t)Cc * Cc, kv_part);
    // K2: QK / vPt precompute (sums 8 kv partials; fp32 math, bf16 out).
    precompute<<<512, 256, 0, stream>>>(kv_part, W_attn, W_proj, QKb, vPt);
    // K3: logits GEMM + fused masked softmax -> w. 512 blocks (2/CU), BK=64.
    logits_softmax<<<dim3(HK / 64, Tt / 32, Bb), 256, 0, stream>>>(x, QKb, w_ws);
    // K4: out = w @ vPt^T -> d_out fp32. 1024 blocks (4/CU).
    out_gemm<<<dim3(16, 16, Bb), 256, 0, stream>>>(w_ws, vPt, out);
}